// Round 2
// baseline (445.685 us; speedup 1.0000x reference)
//
#include <hip/hip_runtime.h>
#include <hip/hip_bf16.h>
#include <cstddef>

#define EPSV 1e-5f

typedef __attribute__((ext_vector_type(2))) short short2v;
typedef __attribute__((ext_vector_type(4))) short short4v;

__device__ __forceinline__ float b2f(short s) {
  union { unsigned u; float f; } x;
  x.u = ((unsigned)(unsigned short)s) << 16;
  return x.f;
}
__device__ __forceinline__ short f2b(float f) {
  __hip_bfloat16 h = __float2bfloat16(f);   // RNE rounding
  union { __hip_bfloat16 h; short s; } x;
  x.h = h;
  return x.s;
}

// x (16,128,56,56) -> xb (896,128,56): xb[n*56+w][c][h] = x[n][c][h][w]
__global__ __launch_bounds__(256) void k_transpose_in(const float* __restrict__ x,
                                                      float* __restrict__ xb) {
  int nc = blockIdx.x;               // n*128 + c
  int n = nc >> 7, c = nc & 127;
  __shared__ float t[56][57];
  const float* src = x + (size_t)nc * 3136;
  for (int idx = threadIdx.x; idx < 3136; idx += 256)
    t[idx / 56][idx % 56] = src[idx];        // coalesced read (w contiguous)
  __syncthreads();
  for (int idx = threadIdx.x; idx < 3136; idx += 256) {
    int w = idx / 56, h = idx - w * 56;
    xb[((size_t)(n * 56 + w) * 128 + c) * 56 + h] = t[h][w];  // coalesced write (h contiguous)
  }
}

// tmp (896,128,56) -> out (16,128,56,56): out[n][c][h][w] = tmp[n*56+w][c][h]
__global__ __launch_bounds__(256) void k_transpose_out(const float* __restrict__ tmp,
                                                       float* __restrict__ out) {
  int nc = blockIdx.x;
  int n = nc >> 7, c = nc & 127;
  __shared__ float t[56][57];
  for (int idx = threadIdx.x; idx < 3136; idx += 256) {
    int w = idx / 56, h = idx - w * 56;
    t[h][w] = tmp[((size_t)(n * 56 + w) * 128 + c) * 56 + h];  // coalesced read
  }
  __syncthreads();
  float* dst = out + (size_t)nc * 3136;
  for (int idx = threadIdx.x; idx < 3136; idx += 256)
    dst[idx] = t[idx / 56][idx % 56];        // coalesced write
}

// One block per (b,g). bid = g*896 + b  (896%8==0 -> same-b blocks share XCD L2).
// LDS budget ~37.9 KB -> 4 blocks/CU (16 waves/CU).
__global__ __launch_bounds__(256) void k_fused(
    const float* __restrict__ xb, const float* __restrict__ wq,
    const float* __restrict__ rel,
    const float* __restrict__ qg, const float* __restrict__ qb,
    const float* __restrict__ qm, const float* __restrict__ qv,
    const float* __restrict__ sg, const float* __restrict__ sb,
    const float* __restrict__ sm, const float* __restrict__ svar,
    const float* __restrict__ og, const float* __restrict__ ob,
    const float* __restrict__ om, const float* __restrict__ ov,
    float* __restrict__ tmp) {
  const int tid = threadIdx.x;
  const int g = blockIdx.x / 896;
  const int b = blockIdx.x - g * 896;

  // union region: stage1 {xs bf16 [128][56] + WT bf16 [128][32]} = 22528 B
  //               stage2+ {sim f32 [56][56] + simT bf16 [56][60]} = 19264 B
  __shared__ __align__(16) float s_un[5632];       // 22528 B
  __shared__ __align__(16) short s_rel[32 * 112];  // bf16, 7168 B
  __shared__ __align__(16) float s_qkv[32 * 60];   // f32, stride 60, 7680 B
  __shared__ float s_qsc[32], s_qsh[32], s_osc[32], s_osh[32], s_ssc[3], s_ssh[3];

  short* xs   = (short*)s_un;            // bf16 [128][56]
  short* WT   = (short*)s_un + 7168;     // bf16 [128][32], c-major (transposed W)
  float* sim  = s_un;                    // f32 [56][56]
  short* simT = (short*)(s_un + 3136);   // bf16 [56][60], simT[j][i]

  // ---------- stage 0: staging ----------
  {
    const float4* src = (const float4*)(xb + (size_t)b * 7168);
#pragma unroll
    for (int i = 0; i < 7; ++i) {
      float4 v = src[tid + i * 256];
      short4v s;
      s.x = f2b(v.x); s.y = f2b(v.y); s.z = f2b(v.z); s.w = f2b(v.w);
      *(short4v*)&xs[4 * (tid + i * 256)] = s;
    }
    // W transpose: lane op = tid&31 -> contiguous o on LDS writes (conflict-free);
    // global reads stride 128 floats but W (16KB) is L2-hot across 896 blocks.
    {
      const int op = tid & 31;
      const int cq = tid >> 5;
#pragma unroll
      for (int rep = 0; rep < 4; ++rep) {
        const int c0 = (cq + rep * 8) * 4;
        const float4 wv = *(const float4*)&wq[g * 4096 + op * 128 + c0];
        WT[(c0 + 0) * 32 + op] = f2b(wv.x);
        WT[(c0 + 1) * 32 + op] = f2b(wv.y);
        WT[(c0 + 2) * 32 + op] = f2b(wv.z);
        WT[(c0 + 3) * 32 + op] = f2b(wv.w);
      }
    }
    for (int i = tid; i < 3552; i += 256) {
      int r = i / 111;
      s_rel[r * 112 + (i - r * 111)] = f2b(rel[i]);
    }
    if (tid < 32) {
      int ch = g * 32 + tid;
      float sc = qg[ch] * rsqrtf(qv[ch] + EPSV);
      s_qsc[tid] = sc;
      s_qsh[tid] = qb[ch] - qm[ch] * sc;
      float so = og[ch] * rsqrtf(ov[ch] + EPSV);
      s_osc[tid] = so;
      s_osh[tid] = ob[ch] - om[ch] * so;
    }
    if (tid < 3) {
      int ch = tid * 8 + g;     // stacked sim channels: qk=g, qr=8+g, kr=16+g
      float ss = sg[ch] * rsqrtf(svar[ch] + EPSV);
      s_ssc[tid] = ss;
      s_ssh[tid] = sb[ch] - sm[ch] * ss;
    }
  }
  __syncthreads();

  // ---------- stage 1: qkv = BN(W_g @ xb[b]), 32x56, fp32 accum ----------
  if (tid < 224) {
    const int o0 = (tid / 14) * 2;     // 0,2,...,30
    const int h0 = (tid % 14) * 4;     // 0,4,...,52
    float a00 = 0, a01 = 0, a02 = 0, a03 = 0;
    float a10 = 0, a11 = 0, a12 = 0, a13 = 0;
    for (int c = 0; c < 128; ++c) {
      const short4v xv = *(const short4v*)&xs[c * 56 + h0];   // b64, conflict-free
      const short2v wv = *(const short2v*)&WT[c * 32 + o0];   // b32, conflict-free
      const float x0 = b2f(xv.x), x1 = b2f(xv.y), x2 = b2f(xv.z), x3 = b2f(xv.w);
      const float w0 = b2f(wv.x), w1 = b2f(wv.y);
      a00 = fmaf(w0, x0, a00); a01 = fmaf(w0, x1, a01);
      a02 = fmaf(w0, x2, a02); a03 = fmaf(w0, x3, a03);
      a10 = fmaf(w1, x0, a10); a11 = fmaf(w1, x1, a11);
      a12 = fmaf(w1, x2, a12); a13 = fmaf(w1, x3, a13);
    }
    float sc = s_qsc[o0], sh = s_qsh[o0];
    s_qkv[o0 * 60 + h0 + 0] = fmaf(a00, sc, sh);
    s_qkv[o0 * 60 + h0 + 1] = fmaf(a01, sc, sh);
    s_qkv[o0 * 60 + h0 + 2] = fmaf(a02, sc, sh);
    s_qkv[o0 * 60 + h0 + 3] = fmaf(a03, sc, sh);
    sc = s_qsc[o0 + 1]; sh = s_qsh[o0 + 1];
    s_qkv[(o0 + 1) * 60 + h0 + 0] = fmaf(a10, sc, sh);
    s_qkv[(o0 + 1) * 60 + h0 + 1] = fmaf(a11, sc, sh);
    s_qkv[(o0 + 1) * 60 + h0 + 2] = fmaf(a12, sc, sh);
    s_qkv[(o0 + 1) * 60 + h0 + 3] = fmaf(a13, sc, sh);
  }
  __syncthreads();

  // ---------- stage 2: sim[i][j] = bnA(qk)+bnB(qr)+bnC(kr), fp32 ----------
  {
    const float scA = s_ssc[0], shA = s_ssh[0];
    const float scB = s_ssc[1], shB = s_ssh[1];
    const float scC = s_ssc[2], shC = s_ssh[2];
    for (int t = tid; t < 784; t += 256) {
      const int i = t / 14;
      const int j0 = (t - i * 14) * 4;
      float qk0 = 0, qk1 = 0, qk2 = 0, qk3 = 0;
      float qr0 = 0, qr1 = 0, qr2 = 0, qr3 = 0;
      float kr0 = 0, kr1 = 0, kr2 = 0, kr3 = 0;
#pragma unroll
      for (int c = 0; c < 8; ++c) {
        const float qi = s_qkv[c * 60 + i];
        const float4 kj = *(const float4*)&s_qkv[(8 + c) * 60 + j0];
        const short* rq = &s_rel[c * 112 + i - j0 + 55];        // rq[-dj] = rel[c][i-(j0+dj)+55]
        const short* rk = &s_rel[(8 + c) * 112 + j0 - i + 55];  // rk[dj]  = rel[8+c][(j0+dj)-i+55]
        qk0 = fmaf(qi, kj.x, qk0); qk1 = fmaf(qi, kj.y, qk1);
        qk2 = fmaf(qi, kj.z, qk2); qk3 = fmaf(qi, kj.w, qk3);
        qr0 = fmaf(qi, b2f(rq[0]), qr0);  qr1 = fmaf(qi, b2f(rq[-1]), qr1);
        qr2 = fmaf(qi, b2f(rq[-2]), qr2); qr3 = fmaf(qi, b2f(rq[-3]), qr3);
        kr0 = fmaf(kj.x, b2f(rk[0]), kr0); kr1 = fmaf(kj.y, b2f(rk[1]), kr1);
        kr2 = fmaf(kj.z, b2f(rk[2]), kr2); kr3 = fmaf(kj.w, b2f(rk[3]), kr3);
      }
      float4 o4;
      o4.x = fmaf(qk0, scA, shA) + fmaf(qr0, scB, shB) + fmaf(kr0, scC, shC);
      o4.y = fmaf(qk1, scA, shA) + fmaf(qr1, scB, shB) + fmaf(kr1, scC, shC);
      o4.z = fmaf(qk2, scA, shA) + fmaf(qr2, scB, shB) + fmaf(kr2, scC, shC);
      o4.w = fmaf(qk3, scA, shA) + fmaf(qr3, scB, shB) + fmaf(kr3, scC, shC);
      *(float4*)&sim[i * 56 + j0] = o4;
    }
  }
  __syncthreads();

  // ---------- stage 3: row softmax (axis j) + transpose into simT (bf16) ----------
  {
    const int lane = tid & 63;
    const int wv = tid >> 6;
    for (int i = wv; i < 56; i += 4) {
      float v = (lane < 56) ? sim[i * 56 + lane] : -3.0e38f;
      float m = v;
#pragma unroll
      for (int off = 32; off > 0; off >>= 1) m = fmaxf(m, __shfl_xor(m, off));
      float e = (lane < 56) ? __expf(v - m) : 0.0f;
      float s = e;
#pragma unroll
      for (int off = 32; off > 0; off >>= 1) s += __shfl_xor(s, off);
      if (lane < 56) simT[lane * 60 + i] = f2b(e / s);
    }
  }
  __syncthreads();

  // ---------- stage 4: sv/sve + out BN + pair-sum, write tmp[b][g*16+c][i] ----------
  if (tid < 224) {
    const int c = tid / 14;                 // 0..15
    const int i0 = (tid - c * 14) * 4;
    float sv0 = 0, sv1 = 0, sv2 = 0, sv3 = 0;
    float se0 = 0, se1 = 0, se2 = 0, se3 = 0;
    const float* vrow = &s_qkv[(16 + c) * 60];
    const short* rv = &s_rel[(16 + c) * 112 + 55 + i0];  // (rv - j)[di] = rel[16+c][(i0+di)-j+55]
    for (int j = 0; j < 56; ++j) {
      const float vj = vrow[j];
      const short4v p4 = *(const short4v*)&simT[j * 60 + i0];  // b64, conflict-free
      const float p0 = b2f(p4.x), p1 = b2f(p4.y), p2 = b2f(p4.z), p3 = b2f(p4.w);
      const short* r = rv - j;
      sv0 = fmaf(p0, vj, sv0); sv1 = fmaf(p1, vj, sv1);
      sv2 = fmaf(p2, vj, sv2); sv3 = fmaf(p3, vj, sv3);
      se0 = fmaf(p0, b2f(r[0]), se0); se1 = fmaf(p1, b2f(r[1]), se1);
      se2 = fmaf(p2, b2f(r[2]), se2); se3 = fmaf(p3, b2f(r[3]), se3);
    }
    const float sc0 = s_osc[2 * c],     sh0 = s_osh[2 * c];
    const float sc1 = s_osc[2 * c + 1], sh1 = s_osh[2 * c + 1];
    float4 o4;
    o4.x = fmaf(sv0, sc0, sh0) + fmaf(se0, sc1, sh1);
    o4.y = fmaf(sv1, sc0, sh0) + fmaf(se1, sc1, sh1);
    o4.z = fmaf(sv2, sc0, sh0) + fmaf(se2, sc1, sh1);
    o4.w = fmaf(sv3, sc0, sh0) + fmaf(se3, sc1, sh1);
    const int oc = g * 16 + c;
    *(float4*)&tmp[((size_t)b * 128 + oc) * 56 + i0] = o4;
  }
}

extern "C" void kernel_launch(void* const* d_in, const int* in_sizes, int n_in,
                              void* d_out, int out_size, void* d_ws, size_t ws_size,
                              hipStream_t stream) {
  const float* x   = (const float*)d_in[0];
  const float* wq  = (const float*)d_in[1];
  const float* rel = (const float*)d_in[2];
  const float* qg = (const float*)d_in[3];
  const float* qb = (const float*)d_in[4];
  const float* qm = (const float*)d_in[5];
  const float* qv = (const float*)d_in[6];
  const float* sg = (const float*)d_in[7];
  const float* sb = (const float*)d_in[8];
  const float* sm = (const float*)d_in[9];
  const float* sv = (const float*)d_in[10];
  const float* og = (const float*)d_in[11];
  const float* ob = (const float*)d_in[12];
  const float* om = (const float*)d_in[13];
  const float* ov = (const float*)d_in[14];
  float* out = (float*)d_out;

  // Reuse d_out as the xb staging buffer (same size: 896*128*56 floats);
  // workspace holds tmp (25.7 MB).
  float* xbuf = out;
  float* tmp = (float*)d_ws;

  k_transpose_in<<<2048, 256, 0, stream>>>(x, xbuf);
  k_fused<<<7168, 256, 0, stream>>>(xbuf, wq, rel,
                                    qg, qb, qm, qv,
                                    sg, sb, sm, sv,
                                    og, ob, om, ov, tmp);
  k_transpose_out<<<2048, 256, 0, stream>>>(tmp, out);
}

// Round 5
// 306.082 us; speedup vs baseline: 1.4561x; 1.4561x over previous
//
#include <hip/hip_runtime.h>
#include <hip/hip_bf16.h>
#include <cstddef>

#define EPSV 1e-5f

typedef __attribute__((ext_vector_type(8))) short bf16x8;
typedef __attribute__((ext_vector_type(4))) float f32x4;
typedef __attribute__((ext_vector_type(4))) short short4v;
typedef __attribute__((ext_vector_type(4))) int int4v;

__device__ __forceinline__ float b2f(short s) {
  union { unsigned u; float f; } x;
  x.u = ((unsigned)(unsigned short)s) << 16;
  return x.f;
}
__device__ __forceinline__ short f2b(float f) {
  union { __hip_bfloat16 h; short s; } x;
  x.h = __float2bfloat16(f);
  return x.s;
}

// x (16,128,56,56) -> xb (896,128,56): xb[n*56+w][c][h] = x[n][c][h][w]
__global__ __launch_bounds__(256) void k_transpose_in(const float* __restrict__ x,
                                                      float* __restrict__ xb) {
  int nc = blockIdx.x;               // n*128 + c
  int n = nc >> 7, c = nc & 127;
  __shared__ float t[56][57];
  const float* src = x + (size_t)nc * 3136;
  for (int idx = threadIdx.x; idx < 3136; idx += 256)
    t[idx / 56][idx % 56] = src[idx];
  __syncthreads();
  for (int idx = threadIdx.x; idx < 3136; idx += 256) {
    int w = idx / 56, h = idx - w * 56;
    xb[((size_t)(n * 56 + w) * 128 + c) * 56 + h] = t[h][w];
  }
}

// tmp (896,128,56) -> out (16,128,56,56): out[n][c][h][w] = tmp[n*56+w][c][h]
__global__ __launch_bounds__(256) void k_transpose_out(const float* __restrict__ tmp,
                                                       float* __restrict__ out) {
  int nc = blockIdx.x;
  int n = nc >> 7, c = nc & 127;
  __shared__ float t[56][57];
  for (int idx = threadIdx.x; idx < 3136; idx += 256) {
    int w = idx / 56, h = idx - w * 56;
    t[h][w] = tmp[((size_t)(n * 56 + w) * 128 + c) * 56 + h];
  }
  __syncthreads();
  float* dst = out + (size_t)nc * 3136;
  for (int idx = threadIdx.x; idx < 3136; idx += 256)
    dst[idx] = t[idx / 56][idx % 56];
}

// LDS arena (offsets in shorts).
//  [0,7616):      xsT bf16 [56][136]            -> sim f32 [56][56] (phase C)
//  [7616,12224):  Ws bf16 [32][136] (to 11968)  -> simA bf16 [64][72] (phase C+)
//  [12224,20928): simShift bf16 [64][136]       (phase C+)
//  [20928,24768): qkv f32 [16][60] (B/C)        -> svL/sveL f32 [16][60] each (phase D+)
//  [24768,26560): s_rel bf16 [16][112]  (q,k channels, logit VALU)
//  [26560,28736): relv bf16 [16][136]   (zero-padded, sve MFMA A)
//  [28736,29888): VBH bf16 [16][72]
//  [29888,31040): VBL bf16 [16][72]
#define O_XST    0
#define O_WS     7616
#define O_SIMA   7616
#define O_SHFT   12224
#define O_QKV    20928
#define O_SVL    20928
#define O_SVEL   22848
#define O_REL    24768
#define O_RELV   26560
#define O_VBH    28736
#define O_VBL    29888
#define SB_SH    31040

// One block per (b,g): bid = g*896 + b (896%8==0 -> same-b blocks share XCD L2).
__global__ __launch_bounds__(512) void k_fused(
    const float* __restrict__ xb, const float* __restrict__ wq,
    const float* __restrict__ rel,
    const float* __restrict__ qg, const float* __restrict__ qb,
    const float* __restrict__ qm, const float* __restrict__ qv,
    const float* __restrict__ sg, const float* __restrict__ sb,
    const float* __restrict__ sm, const float* __restrict__ svar,
    const float* __restrict__ og, const float* __restrict__ ob,
    const float* __restrict__ om, const float* __restrict__ ov,
    float* __restrict__ tmp) {
  const int tid = threadIdx.x;
  const int g = blockIdx.x / 896;
  const int b = blockIdx.x - g * 896;

  __shared__ __align__(16) short SB[SB_SH];
  __shared__ float s_qsc[32], s_qsh[32], s_osc[32], s_osh[32], s_ssc[3], s_ssh[3];

  const int lane = tid & 63;
  const int w = tid >> 6;          // wave 0..7
  const int m = lane & 15;
  const int qd = lane >> 4;        // 0..3
  const int it = w >> 1;           // tile row group 0..3
  const int half = w & 1;

  // ---------- phase A: zero pads; stage xsT, Ws, rel, BN params ----------
  {
    int4v z = {0, 0, 0, 0};
    int4v* zp = (int4v*)(SB + O_RELV);          // zero RELV+VBH+VBL = 4480 sh
    for (int i = tid; i < 560; i += 512) zp[i] = z;

    const float* xg = xb + (size_t)b * 7168;
    for (int t = tid; t < 896; t += 512) {
      int cp = t / 14, hq = t - cp * 14;
      int c0 = cp * 2, h0 = hq * 4;
      float4 xa = *(const float4*)&xg[c0 * 56 + h0];
      float4 xc = *(const float4*)&xg[c0 * 56 + 56 + h0];
      float a4[4] = {xa.x, xa.y, xa.z, xa.w};
      float c4[4] = {xc.x, xc.y, xc.z, xc.w};
#pragma unroll
      for (int e = 0; e < 4; ++e) {
        unsigned lo = (unsigned short)f2b(a4[e]);
        unsigned hi = (unsigned short)f2b(c4[e]);
        *(unsigned*)&SB[O_XST + (h0 + e) * 136 + c0] = lo | (hi << 16);
      }
    }
    for (int t = tid; t < 1024; t += 512) {
      int o = t >> 5, c0 = (t & 31) * 4;
      float4 wv = *(const float4*)&wq[g * 4096 + o * 128 + c0];
      short4v s4 = {f2b(wv.x), f2b(wv.y), f2b(wv.z), f2b(wv.w)};
      *(short4v*)&SB[O_WS + o * 136 + c0] = s4;
    }
    for (int t = tid; t < 3552; t += 512) {
      int c = t / 111, d = t - c * 111;
      short v = f2b(rel[t]);
      if (c < 16) SB[O_REL + c * 112 + d] = v;
      else        SB[O_RELV + (c - 16) * 136 + d] = v;
    }
    if (tid < 32) {
      int ch = g * 32 + tid;
      float sc = qg[ch] * rsqrtf(qv[ch] + EPSV);
      s_qsc[tid] = sc;
      s_qsh[tid] = qb[ch] - qm[ch] * sc;
      float so = og[ch] * rsqrtf(ov[ch] + EPSV);
      s_osc[tid] = so;
      s_osh[tid] = ob[ch] - om[ch] * so;
    }
    if (tid < 3) {
      int ch = tid * 8 + g;
      float ss = sg[ch] * rsqrtf(svar[ch] + EPSV);
      s_ssc[tid] = ss;
      s_ssh[tid] = sb[ch] - sm[ch] * ss;
    }
  }
  __syncthreads();   // B0

  // ---------- phase B: qkv = BN(W @ x) via MFMA; q,k -> f32 LDS, v -> bf16 hi/lo ----------
  {
    const int ot = half;
    const int o = ot * 16 + m;
    const int h = it * 16 + m;
    f32x4 acc = {0.f, 0.f, 0.f, 0.f};
#pragma unroll
    for (int ks = 0; ks < 4; ++ks) {
      bf16x8 av = *(bf16x8*)&SB[O_WS + o * 136 + qd * 8 + ks * 32];
      bf16x8 bv = *(bf16x8*)&SB[O_XST + h * 136 + qd * 8 + ks * 32];
      acc = __builtin_amdgcn_mfma_f32_16x16x32_bf16(av, bv, acc, 0, 0, 0);
    }
    if (h < 56) {                    // D col = h; D row = oo
      float* qkvF = (float*)(SB + O_QKV);
#pragma unroll
      for (int r = 0; r < 4; ++r) {
        int oo = ot * 16 + qd * 4 + r;
        float val = fmaf(acc[r], s_qsc[oo], s_qsh[oo]);
        if (oo < 16) {
          qkvF[oo * 60 + h] = val;           // q rows 0..7, k rows 8..15 (f32)
        } else {
          short vh = f2b(val);
          short vl = f2b(val - b2f(vh));
          SB[O_VBH + (oo - 16) * 72 + h] = vh;
          SB[O_VBL + (oo - 16) * 72 + h] = vl;
        }
      }
    }
  }
  __syncthreads();   // B1

  // ---------- phase C1: zero simA+simShift; logits via VALU (round-2 code) ----------
  {
    int4v z = {0, 0, 0, 0};
    int4v* zp = (int4v*)(SB + O_SIMA);          // 13312 sh = 1664 int4
    for (int i = tid; i < 1664; i += 512) zp[i] = z;
  }
  {
    float* sim = (float*)SB;                    // f32 [56][56] over dead xsT
    const float* qk_ = (const float*)(SB + O_QKV);
    const float scA = s_ssc[0], shA = s_ssh[0];
    const float scB = s_ssc[1], shB = s_ssh[1];
    const float scC = s_ssc[2], shC = s_ssh[2];
    for (int t = tid; t < 784; t += 512) {
      const int i = t / 14;
      const int j0 = (t - i * 14) * 4;
      float qk0 = 0, qk1 = 0, qk2 = 0, qk3 = 0;
      float qr0 = 0, qr1 = 0, qr2 = 0, qr3 = 0;
      float kr0 = 0, kr1 = 0, kr2 = 0, kr3 = 0;
#pragma unroll
      for (int c = 0; c < 8; ++c) {
        const float qi = qk_[c * 60 + i];
        const float4 kj = *(const float4*)&qk_[(8 + c) * 60 + j0];
        const short* rq = &SB[O_REL + c * 112 + i - j0 + 55];        // rq[-dj] = rel[c][i-(j0+dj)+55]
        const short* rk = &SB[O_REL + (8 + c) * 112 + j0 - i + 55];  // rk[dj]  = rel[8+c][(j0+dj)-i+55]
        qk0 = fmaf(qi, kj.x, qk0); qk1 = fmaf(qi, kj.y, qk1);
        qk2 = fmaf(qi, kj.z, qk2); qk3 = fmaf(qi, kj.w, qk3);
        qr0 = fmaf(qi, b2f(rq[0]), qr0);  qr1 = fmaf(qi, b2f(rq[-1]), qr1);
        qr2 = fmaf(qi, b2f(rq[-2]), qr2); qr3 = fmaf(qi, b2f(rq[-3]), qr3);
        kr0 = fmaf(kj.x, b2f(rk[0]), kr0); kr1 = fmaf(kj.y, b2f(rk[1]), kr1);
        kr2 = fmaf(kj.z, b2f(rk[2]), kr2); kr3 = fmaf(kj.w, b2f(rk[3]), kr3);
      }
      float4 o4;
      o4.x = fmaf(qk0, scA, shA) + fmaf(qr0, scB, shB) + fmaf(kr0, scC, shC);
      o4.y = fmaf(qk1, scA, shA) + fmaf(qr1, scB, shB) + fmaf(kr1, scC, shC);
      o4.z = fmaf(qk2, scA, shA) + fmaf(qr2, scB, shB) + fmaf(kr2, scC, shC);
      o4.w = fmaf(qk3, scA, shA) + fmaf(qr3, scB, shB) + fmaf(kr3, scC, shC);
      *(float4*)&sim[i * 56 + j0] = o4;
    }
  }
  __syncthreads();   // B2

  // ---------- phase C2: row softmax (round-2 code), scatter P -> simA + simShift ----------
  {
    const float* sim = (const float*)SB;
    const int wv8 = tid >> 6;
    for (int i = wv8; i < 56; i += 8) {
      float v = (lane < 56) ? sim[i * 56 + lane] : -3.0e38f;
      float mx = v;
#pragma unroll
      for (int off = 32; off > 0; off >>= 1) mx = fmaxf(mx, __shfl_xor(mx, off));
      float e = (lane < 56) ? __expf(v - mx) : 0.0f;
      float s = e;
#pragma unroll
      for (int off = 32; off > 0; off >>= 1) s += __shfl_xor(s, off);
      if (lane < 56) {
        short pv = f2b(e / s);
        SB[O_SIMA + i * 72 + lane] = pv;                 // simA[i][j]
        SB[O_SHFT + i * 136 + (i - lane + 55)] = pv;     // simShift[i][i-j+55]
      }
    }
  }
  __syncthreads();   // B3

  // ---------- phase D: sv = P @ (vh+vl)^T (even waves), sve = relv @ simShift^T (odd) ----------
  {
    if (half == 0) {
      bf16x8 pa0 = *(bf16x8*)&SB[O_SIMA + (it * 16 + m) * 72 + qd * 8];
      bf16x8 pa1 = *(bf16x8*)&SB[O_SIMA + (it * 16 + m) * 72 + qd * 8 + 32];
      f32x4 acc = {0.f, 0.f, 0.f, 0.f};
      bf16x8 bv;
      bv = *(bf16x8*)&SB[O_VBH + m * 72 + qd * 8];
      acc = __builtin_amdgcn_mfma_f32_16x16x32_bf16(pa0, bv, acc, 0, 0, 0);
      bv = *(bf16x8*)&SB[O_VBH + m * 72 + qd * 8 + 32];
      acc = __builtin_amdgcn_mfma_f32_16x16x32_bf16(pa1, bv, acc, 0, 0, 0);
      bv = *(bf16x8*)&SB[O_VBL + m * 72 + qd * 8];
      acc = __builtin_amdgcn_mfma_f32_16x16x32_bf16(pa0, bv, acc, 0, 0, 0);
      bv = *(bf16x8*)&SB[O_VBL + m * 72 + qd * 8 + 32];
      acc = __builtin_amdgcn_mfma_f32_16x16x32_bf16(pa1, bv, acc, 0, 0, 0);
      float* svLf = (float*)(SB + O_SVL);
#pragma unroll
      for (int r = 0; r < 4; ++r) {
        int i2 = it * 16 + qd * 4 + r;             // D row = i
        if (i2 < 56) svLf[m * 60 + i2] = acc[r];   // D col = c = m
      }
    } else {
      f32x4 acc = {0.f, 0.f, 0.f, 0.f};
#pragma unroll
      for (int ks = 0; ks < 4; ++ks) {
        bf16x8 av = *(bf16x8*)&SB[O_RELV + m * 136 + qd * 8 + ks * 32];
        bf16x8 bv = *(bf16x8*)&SB[O_SHFT + (it * 16 + m) * 136 + qd * 8 + ks * 32];
        acc = __builtin_amdgcn_mfma_f32_16x16x32_bf16(av, bv, acc, 0, 0, 0);
      }
      float* sveLf = (float*)(SB + O_SVEL);
#pragma unroll
      for (int r = 0; r < 4; ++r) {
        int i2 = it * 16 + m;              // D col = i
        int cv = qd * 4 + r;               // D row = cv
        if (i2 < 56) sveLf[cv * 60 + i2] = acc[r];
      }
    }
  }
  __syncthreads();   // B4

  // ---------- phase E: final BN-combine + store tmp[b][g*16+c][i] ----------
  if (tid < 448) {
    const float* svLf = (const float*)(SB + O_SVL);
    const float* sveLf = (const float*)(SB + O_SVEL);
    int c = tid / 28, t2 = tid - c * 28;
    int i0 = t2 * 2;
    float sc0 = s_osc[2 * c], sh0 = s_osh[2 * c];
    float sc1 = s_osc[2 * c + 1], sh1 = s_osh[2 * c + 1];
    float2 o2;
    o2.x = fmaf(svLf[c * 60 + i0],     sc0, sh0) + fmaf(sveLf[c * 60 + i0],     sc1, sh1);
    o2.y = fmaf(svLf[c * 60 + i0 + 1], sc0, sh0) + fmaf(sveLf[c * 60 + i0 + 1], sc1, sh1);
    *(float2*)&tmp[((size_t)b * 128 + g * 16 + c) * 56 + i0] = o2;
  }
}

extern "C" void kernel_launch(void* const* d_in, const int* in_sizes, int n_in,
                              void* d_out, int out_size, void* d_ws, size_t ws_size,
                              hipStream_t stream) {
  const float* x   = (const float*)d_in[0];
  const float* wq  = (const float*)d_in[1];
  const float* rel = (const float*)d_in[2];
  const float* qg = (const float*)d_in[3];
  const float* qb = (const float*)d_in[4];
  const float* qm = (const float*)d_in[5];
  const float* qv = (const float*)d_in[6];
  const float* sg = (const float*)d_in[7];
  const float* sb = (const float*)d_in[8];
  const float* sm = (const float*)d_in[9];
  const float* sv = (const float*)d_in[10];
  const float* og = (const float*)d_in[11];
  const float* ob = (const float*)d_in[12];
  const float* om = (const float*)d_in[13];
  const float* ov = (const float*)d_in[14];
  float* out = (float*)d_out;

  float* xbuf = out;            // reuse d_out as xb staging (same size)
  float* tmp = (float*)d_ws;    // 25.7 MB

  k_transpose_in<<<2048, 256, 0, stream>>>(x, xbuf);
  k_fused<<<7168, 512, 0, stream>>>(xbuf, wq, rel,
                                    qg, qb, qm, qv,
                                    sg, sb, sm, sv,
                                    og, ob, om, ov, tmp);
  k_transpose_out<<<2048, 256, 0, stream>>>(tmp, out);
}